// Round 9
// baseline (158.478 us; speedup 1.0000x reference)
//
#include <hip/hip_runtime.h>

#define DIM 64
#define NB 4096
#define NTOK 32
#define BPB 8     // batch elements per block

typedef __attribute__((ext_vector_type(8))) __bf16 bf16x8;
typedef __attribute__((ext_vector_type(4))) float f32x4;

__device__ __forceinline__ f32x4 mfma16(bf16x8 a, bf16x8 b, f32x4 c) {
  return __builtin_amdgcn_mfma_f32_16x16x32_bf16(a, b, c, 0, 0, 0);
}

// LDS XOR swizzle: keeps 16B blocks contiguous, bank conflicts measured 0.
#define SWC(row, col) ((col) ^ (((row) & 7) << 3))

// Transpose weights to bf16 [col][k] in ws (48 KB):
// W1t[64][128], G1t[64][128], W2t[64][64], G2t[64][64]
__global__ void prep_w(const float* __restrict__ W1, const float* __restrict__ G1,
                       const float* __restrict__ W2, const float* __restrict__ G2,
                       __bf16* __restrict__ ws) {
  int i = blockIdx.x * 256 + threadIdx.x;
  if (i < 8192) {
    int c = i >> 7, k = i & 127;
    ws[i]        = (__bf16)W1[k * 64 + c];
    ws[8192 + i] = (__bf16)G1[k * 64 + c];
  } else if (i < 12288) {
    int j = i - 8192;
    int c = j >> 6, k = j & 63;
    ws[16384 + j] = (__bf16)W2[k * 64 + c];
    ws[20480 + j] = (__bf16)G2[k * 64 + c];
  }
}

// R9: cross-iteration software pipeline. Block = 8 batch elements, 4 waves =
// 4 (l,tower) combos. At the top of iteration it: issue t_e gathers for elem
// it AND A-gathers (+io row) for elem it+1; convert to bf16 only after the
// S path (~1200cy window). GEMM1 for elem it has zero load dependency.
// G path before S path so accG retires while the 80-reg prefetch window is
// open. R8 post-mortem: dur finally moved (-13%) with MLP/prefetch; this
// closes the last exposed window. If null -> latency/clock floor.
// Register history: plain __launch_bounds__(256) -> no spill; min-waves arg
// forced VGPR below live accs -> 184-547 MB scratch storms (R2/R3).
__global__ __launch_bounds__(256) void ckan_fast(
    const int* __restrict__ items, const int* __restrict__ user_h,
    const int* __restrict__ user_r, const int* __restrict__ user_t,
    const int* __restrict__ item_h, const int* __restrict__ item_r,
    const int* __restrict__ item_t,
    const float* __restrict__ ent, const float* __restrict__ rel,
    const __bf16* __restrict__ wsb, const float* __restrict__ w3,
    float* __restrict__ out)
{
  __shared__ __align__(16) __bf16 buf[128][64];     // 16 KB, wave-private rows
  __shared__ float outbuf[BPB][4][64];               // 8 KB
  __shared__ float pu_lds[BPB];                      // 32 B

  const int tid  = threadIdx.x;
  const int w    = tid >> 6;      // combo: l = w>>1, tower = w&1
  const int lane = tid & 63;
  const int r16  = lane & 15;
  const int g4   = lane >> 4;
  const int rb   = w * 32;        // wave-private LDS rows
  const int b0   = blockIdx.x * BPB;
  const int l    = w >> 1;
  const int tower = w & 1;

  const __bf16* __restrict__ W1t = wsb;
  const __bf16* __restrict__ G1t = wsb + 8192;
  const __bf16* __restrict__ W2t = wsb + 16384;
  const __bf16* __restrict__ G2t = wsb + 20480;

  const int* __restrict__ Hp = tower ? item_h : user_h;
  const int* __restrict__ Rp = tower ? item_r : user_r;
  const int* __restrict__ Tp = tower ? item_t : user_t;

  float w3c[4];
#pragma unroll
  for (int n = 0; n < 4; ++n) w3c[n] = w3[n * 16 + r16];

  const f32x4 zero4 = {0.f, 0.f, 0.f, 0.f};

  // ---- prologue: element 0 (its gather latency is the only exposed one) ----
  int ib = (l * NB + b0) * NTOK;
  int hn0 = Hp[ib + r16] * DIM,      hn1 = Hp[ib + 16 + r16] * DIM;
  int rn0 = Rp[ib + r16] * DIM,      rn1 = Rp[ib + 16 + r16] * DIM;
  int tn0 = Tp[ib + r16] * DIM,      tn1 = Tp[ib + 16 + r16] * DIM;
  int ion = items[b0] * DIM;

  bf16x8 afr[4][2];
  {
    f32x4 axlo[4][2], axhi[4][2], iol[2], ioh[2];
#pragma unroll
    for (int kk = 0; kk < 4; ++kk)
#pragma unroll
      for (int m = 0; m < 2; ++m) {
        const float* src = (kk < 2)
            ? ent + (m ? hn1 : hn0) + kk * 32 + g4 * 8
            : rel + (m ? rn1 : rn0) + (kk - 2) * 32 + g4 * 8;
        axlo[kk][m] = *(const f32x4*)(src);
        axhi[kk][m] = *(const f32x4*)(src + 4);
      }
    if (w == 0) {
#pragma unroll
      for (int h = 0; h < 2; ++h) {
        iol[h] = *(const f32x4*)(ent + ion + h * 32 + g4 * 8);
        ioh[h] = *(const f32x4*)(ent + ion + h * 32 + g4 * 8 + 4);
      }
    }
#pragma unroll
    for (int kk = 0; kk < 4; ++kk)
#pragma unroll
      for (int m = 0; m < 2; ++m) {
        bf16x8 a;
#pragma unroll
        for (int j = 0; j < 4; ++j) {
          a[j]     = (__bf16)axlo[kk][m][j];
          a[4 + j] = (__bf16)axhi[kk][m][j];
        }
        afr[kk][m] = a;
      }
    if (w == 0) {
      float s = 0.f;
#pragma unroll
      for (int j = 0; j < 4; ++j) {
        s += (axlo[0][0][j] + axlo[0][1][j]) * iol[0][j]
           + (axhi[0][0][j] + axhi[0][1][j]) * ioh[0][j]
           + (axlo[1][0][j] + axlo[1][1][j]) * iol[1][j]
           + (axhi[1][0][j] + axhi[1][1][j]) * ioh[1][j];
      }
      s *= (1.f / 32.f);
#pragma unroll
      for (int off = 1; off <= 32; off <<= 1) s += __shfl_xor(s, off);
      if (lane == 0) pu_lds[0] = s;
    }
  }
  int tc0 = tn0, tc1 = tn1;
  // indices for element 1
  ib += NTOK;
  hn0 = Hp[ib + r16] * DIM;  hn1 = Hp[ib + 16 + r16] * DIM;
  rn0 = Rp[ib + r16] * DIM;  rn1 = Rp[ib + 16 + r16] * DIM;
  tn0 = Tp[ib + r16] * DIM;  tn1 = Tp[ib + 16 + r16] * DIM;
  ion = items[b0 + 1] * DIM;

#pragma unroll 1
  for (int it = 0; it < BPB; ++it) {
    const bool more = (it + 1 < BPB);

    // ---- top: issue cur t_e + next A + next io (consumed much later) ----
    f32x4 telo[2][2], tehi[2][2];
#pragma unroll
    for (int m2 = 0; m2 < 2; ++m2)
#pragma unroll
      for (int h = 0; h < 2; ++h) {
        const float* ts = ent + (m2 ? tc1 : tc0) + h * 32 + g4 * 8;
        telo[m2][h] = *(const f32x4*)(ts);
        tehi[m2][h] = *(const f32x4*)(ts + 4);
      }
    f32x4 axlo[4][2], axhi[4][2], iol[2], ioh[2];
    if (more) {
#pragma unroll
      for (int kk = 0; kk < 4; ++kk)
#pragma unroll
        for (int m = 0; m < 2; ++m) {
          const float* src = (kk < 2)
              ? ent + (m ? hn1 : hn0) + kk * 32 + g4 * 8
              : rel + (m ? rn1 : rn0) + (kk - 2) * 32 + g4 * 8;
          axlo[kk][m] = *(const f32x4*)(src);
          axhi[kk][m] = *(const f32x4*)(src + 4);
        }
      if (w == 0) {
#pragma unroll
        for (int h = 0; h < 2; ++h) {
          iol[h] = *(const f32x4*)(ent + ion + h * 32 + g4 * 8);
          ioh[h] = *(const f32x4*)(ent + ion + h * 32 + g4 * 8 + 4);
        }
      }
    }

    // ---- GEMM1 (combined S+G): x[32,128] @ {W1,G1}[128,64] ----
    f32x4 accS[2][4], accG[2][4];
#pragma unroll
    for (int m = 0; m < 2; ++m)
#pragma unroll
      for (int n = 0; n < 4; ++n) { accS[m][n] = zero4; accG[m][n] = zero4; }
#pragma unroll
    for (int kk = 0; kk < 4; ++kk)
#pragma unroll
      for (int n = 0; n < 4; ++n) {
        bf16x8 bS = *(const bf16x8*)(W1t + (n * 16 + r16) * 128 + kk * 32 + g4 * 8);
        bf16x8 bG = *(const bf16x8*)(G1t + (n * 16 + r16) * 128 + kk * 32 + g4 * 8);
#pragma unroll
        for (int m = 0; m < 2; ++m) {
          accS[m][n] = mfma16(afr[kk][m], bS, accS[m][n]);
          accG[m][n] = mfma16(afr[kk][m], bG, accG[m][n]);
        }
      }

    // ---- G path first (retires accG early): relu(g1) -> buf -> GEMM2-G ----
#pragma unroll
    for (int m = 0; m < 2; ++m)
#pragma unroll
      for (int n = 0; n < 4; ++n)
#pragma unroll
        for (int i = 0; i < 4; ++i) {
          const int row = rb + m * 16 + g4 * 4 + i;
          const int col = n * 16 + r16;
          buf[row][SWC(row, col)] = (__bf16)fmaxf(accG[m][n][i], 0.f);
        }
    f32x4 acc2G[2][4];
#pragma unroll
    for (int m = 0; m < 2; ++m)
#pragma unroll
      for (int n = 0; n < 4; ++n) acc2G[m][n] = zero4;
#pragma unroll
    for (int kk = 0; kk < 2; ++kk) {
      bf16x8 aG[2];
#pragma unroll
      for (int m = 0; m < 2; ++m) {
        const int tok = rb + m * 16 + r16;
        aG[m] = *(const bf16x8*)&buf[tok][SWC(tok, kk * 32 + g4 * 8)];
      }
#pragma unroll
      for (int n = 0; n < 4; ++n) {
        bf16x8 bG = *(const bf16x8*)(G2t + (n * 16 + r16) * 64 + kk * 32 + g4 * 8);
#pragma unroll
        for (int m = 0; m < 2; ++m) acc2G[m][n] = mfma16(aG[m], bG, acc2G[m][n]);
      }
    }

    // ---- S path: relu(s1) -> buf (reuse) -> GEMM2-S -> att ----
#pragma unroll
    for (int m = 0; m < 2; ++m)
#pragma unroll
      for (int n = 0; n < 4; ++n)
#pragma unroll
        for (int i = 0; i < 4; ++i) {
          const int row = rb + m * 16 + g4 * 4 + i;
          const int col = n * 16 + r16;
          buf[row][SWC(row, col)] = (__bf16)fmaxf(accS[m][n][i], 0.f);
        }
    f32x4 acc2S[2][4];
#pragma unroll
    for (int m = 0; m < 2; ++m)
#pragma unroll
      for (int n = 0; n < 4; ++n) acc2S[m][n] = zero4;
#pragma unroll
    for (int kk = 0; kk < 2; ++kk) {
      bf16x8 aS[2];
#pragma unroll
      for (int m = 0; m < 2; ++m) {
        const int tok = rb + m * 16 + r16;
        aS[m] = *(const bf16x8*)&buf[tok][SWC(tok, kk * 32 + g4 * 8)];
      }
#pragma unroll
      for (int n = 0; n < 4; ++n) {
        bf16x8 bS = *(const bf16x8*)(W2t + (n * 16 + r16) * 64 + kk * 32 + g4 * 8);
#pragma unroll
        for (int m = 0; m < 2; ++m) acc2S[m][n] = mfma16(aS[m], bS, acc2S[m][n]);
      }
    }

    // s3 + softmax (no max pass: scores are sigmoids in (0,1))
    float att[2][4];
    {
      float dotp[2][4];
#pragma unroll
      for (int m = 0; m < 2; ++m)
#pragma unroll
        for (int i = 0; i < 4; ++i) {
          float d = 0.f;
#pragma unroll
          for (int n = 0; n < 4; ++n)
            d += fmaxf(acc2S[m][n][i], 0.f) * w3c[n];
          dotp[m][i] = d;
        }
#pragma unroll
      for (int off = 1; off <= 8; off <<= 1)
#pragma unroll
        for (int m = 0; m < 2; ++m)
#pragma unroll
          for (int i = 0; i < 4; ++i)
            dotp[m][i] += __shfl_xor(dotp[m][i], off);
      float den = 0.f;
#pragma unroll
      for (int m = 0; m < 2; ++m)
#pragma unroll
        for (int i = 0; i < 4; ++i) {
          const float sc = 1.f / (1.f + __expf(-dotp[m][i]));
          att[m][i] = __expf(sc);
          den += att[m][i];
        }
      den += __shfl_xor(den, 16);
      den += __shfl_xor(den, 32);
      const float inv = 1.f / den;
#pragma unroll
      for (int m = 0; m < 2; ++m)
#pragma unroll
        for (int i = 0; i < 4; ++i) att[m][i] *= inv;
    }

    // ---- pipeline turn: cvt next A -> afr, partU(it+1), rotate indices ----
    if (more) {
#pragma unroll
      for (int kk = 0; kk < 4; ++kk)
#pragma unroll
        for (int m = 0; m < 2; ++m) {
          bf16x8 a;
#pragma unroll
          for (int j = 0; j < 4; ++j) {
            a[j]     = (__bf16)axlo[kk][m][j];
            a[4 + j] = (__bf16)axhi[kk][m][j];
          }
          afr[kk][m] = a;
        }
      if (w == 0) {
        float s = 0.f;
#pragma unroll
        for (int j = 0; j < 4; ++j) {
          s += (axlo[0][0][j] + axlo[0][1][j]) * iol[0][j]
             + (axhi[0][0][j] + axhi[0][1][j]) * ioh[0][j]
             + (axlo[1][0][j] + axlo[1][1][j]) * iol[1][j]
             + (axhi[1][0][j] + axhi[1][1][j]) * ioh[1][j];
        }
        s *= (1.f / 32.f);
#pragma unroll
        for (int off = 1; off <= 32; off <<= 1) s += __shfl_xor(s, off);
        if (lane == 0) pu_lds[it + 1] = s;
      }
      tc0 = tn0; tc1 = tn1;
      if (it + 2 < BPB) {
        ib += NTOK;
        hn0 = Hp[ib + r16] * DIM;  hn1 = Hp[ib + 16 + r16] * DIM;
        rn0 = Rp[ib + r16] * DIM;  rn1 = Rp[ib + 16 + r16] * DIM;
        tn0 = Tp[ib + r16] * DIM;  tn1 = Tp[ib + 16 + r16] * DIM;
        ion = items[b0 + it + 2] * DIM;
      }
    }

    // ---- epilogue: p = att * 2*sigmoid(g2) -> buf; dot with t_e ----
#pragma unroll
    for (int m = 0; m < 2; ++m)
#pragma unroll
      for (int n = 0; n < 4; ++n)
#pragma unroll
        for (int i = 0; i < 4; ++i) {
          const int row = rb + m * 16 + g4 * 4 + i;
          const int col = n * 16 + r16;
          const float g2v = 2.f / (1.f + __expf(-acc2G[m][n][i]));
          buf[row][SWC(row, col)] = (__bf16)(att[m][i] * g2v);
        }

    float dsum[2][8];
#pragma unroll
    for (int h = 0; h < 2; ++h)
#pragma unroll
      for (int j = 0; j < 8; ++j) dsum[h][j] = 0.f;
#pragma unroll
    for (int m2 = 0; m2 < 2; ++m2) {
      const int prow = rb + m2 * 16 + r16;
#pragma unroll
      for (int h = 0; h < 2; ++h) {
        bf16x8 pf = *(const bf16x8*)&buf[prow][SWC(prow, h * 32 + g4 * 8)];
#pragma unroll
        for (int j = 0; j < 4; ++j) {
          dsum[h][j]     += (float)pf[j]     * telo[m2][h][j];
          dsum[h][4 + j] += (float)pf[4 + j] * tehi[m2][h][j];
        }
      }
    }
#pragma unroll
    for (int off = 1; off <= 8; off <<= 1)
#pragma unroll
      for (int h = 0; h < 2; ++h)
#pragma unroll
        for (int j = 0; j < 8; ++j)
          dsum[h][j] += __shfl_xor(dsum[h][j], off);
    if (r16 == 0) {
#pragma unroll
      for (int h = 0; h < 2; ++h)
#pragma unroll
        for (int j = 0; j < 8; ++j)
          outbuf[it][w][h * 32 + g4 * 8 + j] = dsum[h][j];
    }
  }

  __syncthreads();

  // ---- final combine: wave0 scores all BPB elements ----
  if (w == 0) {
#pragma unroll 1
    for (int bb = 0; bb < BPB; ++bb) {
      float part = outbuf[bb][0][lane] * outbuf[bb][1][lane]
                 + outbuf[bb][2][lane] * outbuf[bb][3][lane];
#pragma unroll
      for (int off = 32; off >= 1; off >>= 1) part += __shfl_xor(part, off);
      if (lane == 0) out[b0 + bb] = 1.f / (1.f + __expf(-(part + pu_lds[bb])));
    }
  }
}

extern "C" void kernel_launch(void* const* d_in, const int* in_sizes, int n_in,
                              void* d_out, int out_size, void* d_ws, size_t ws_size,
                              hipStream_t stream) {
  const int*   items  = (const int*)d_in[1];
  const int*   user_h = (const int*)d_in[2];
  const int*   user_r = (const int*)d_in[3];
  const int*   user_t = (const int*)d_in[4];
  const int*   item_h = (const int*)d_in[5];
  const int*   item_r = (const int*)d_in[6];
  const int*   item_t = (const int*)d_in[7];
  const float* ent    = (const float*)d_in[8];
  const float* rel    = (const float*)d_in[9];
  const float* W1     = (const float*)d_in[10];
  const float* W2     = (const float*)d_in[11];
  const float* w3     = (const float*)d_in[12];
  const float* G1     = (const float*)d_in[13];
  const float* G2     = (const float*)d_in[14];
  __bf16* wsb = (__bf16*)d_ws;   // 48 KB used
  float* out = (float*)d_out;

  prep_w<<<dim3(48), dim3(256), 0, stream>>>(W1, G1, W2, G2, wsb);
  ckan_fast<<<dim3(NB / BPB), dim3(256), 0, stream>>>(
      items, user_h, user_r, user_t, item_h, item_r, item_t,
      ent, rel, wsb, w3, out);
}

// Round 10
// 127.982 us; speedup vs baseline: 1.2383x; 1.2383x over previous
//
#include <hip/hip_runtime.h>

#define DIM 64
#define NB 4096
#define NTOK 32
#define BPB 8     // batch elements per block

typedef __attribute__((ext_vector_type(8))) __bf16 bf16x8;
typedef __attribute__((ext_vector_type(4))) __bf16 bf16x4;
typedef __attribute__((ext_vector_type(4))) float f32x4;

__device__ __forceinline__ f32x4 mfma16(bf16x8 a, bf16x8 b, f32x4 c) {
  return __builtin_amdgcn_mfma_f32_16x16x32_bf16(a, b, c, 0, 0, 0);
}

// Transpose weights to bf16 [col][k] in ws (48 KB):
// W1t[64][128], G1t[64][128], W2t[64][64], G2t[64][64]
__global__ void prep_w(const float* __restrict__ W1, const float* __restrict__ G1,
                       const float* __restrict__ W2, const float* __restrict__ G2,
                       __bf16* __restrict__ ws) {
  int i = blockIdx.x * 256 + threadIdx.x;
  if (i < 8192) {
    int c = i >> 7, k = i & 127;
    ws[i]        = (__bf16)W1[k * 64 + c];
    ws[8192 + i] = (__bf16)G1[k * 64 + c];
  } else if (i < 12288) {
    int j = i - 8192;
    int c = j >> 6, k = j & 63;
    ws[16384 + j] = (__bf16)W2[k * 64 + c];
    ws[20480 + j] = (__bf16)G2[k * 64 + c];
  }
}

// R10: operand-swapped GEMMs. s1^T = W1^T @ x^T (weights = A-operand, gathered
// rows = B-operand; loads identical to R8). C-layout then gives each lane 4
// CONSECUTIVE s1-cols (token 16m2+r16, cols 16n+4g4+i) -> LDS staging is 8
// ds_write_b64 + 4 ds_read_b128 per path (was 32 scalar writes), and the
// p-phase LDS round-trip is gone entirely (p*t_e in registers). Softmax row-dot
// is in-lane -> ~8 shuffles vs ~34. R9 lesson: no deep cross-iter prefetch
// (VGPR 256 -> 8.5 MB spill); keep R8 schedule. Register history: plain
// __launch_bounds__(256) -> no spill; min-waves arg -> scratch storms (R2/R3).
__global__ __launch_bounds__(256) void ckan_fast(
    const int* __restrict__ items, const int* __restrict__ user_h,
    const int* __restrict__ user_r, const int* __restrict__ user_t,
    const int* __restrict__ item_h, const int* __restrict__ item_r,
    const int* __restrict__ item_t,
    const float* __restrict__ ent, const float* __restrict__ rel,
    const __bf16* __restrict__ wsb, const float* __restrict__ w3,
    float* __restrict__ out)
{
  // [32][72]: row stride 144B (16B-aligned); b64 writes land 2-way on banks,
  // b128 reads 2-way -> free (m136).
  __shared__ __align__(16) __bf16 buf[4][32][72];    // 18 KB, wave-private
  __shared__ float outbuf[BPB][4][64];                // 8 KB
  __shared__ float pu_lds[BPB];

  const int tid  = threadIdx.x;
  const int w    = tid >> 6;      // combo: l = w>>1, tower = w&1
  const int lane = tid & 63;
  const int r16  = lane & 15;
  const int g4   = lane >> 4;
  const int b0   = blockIdx.x * BPB;
  const int l    = w >> 1;
  const int tower = w & 1;

  const __bf16* __restrict__ W1t = wsb;
  const __bf16* __restrict__ G1t = wsb + 8192;
  const __bf16* __restrict__ W2t = wsb + 16384;
  const __bf16* __restrict__ G2t = wsb + 20480;

  const int* __restrict__ Hp = tower ? item_h : user_h;
  const int* __restrict__ Rp = tower ? item_r : user_r;
  const int* __restrict__ Tp = tower ? item_t : user_t;

  // per-lane w3 slice: w3v[n2][i] = w3[n2*16 + g4*4 + i]
  f32x4 w3v[4];
#pragma unroll
  for (int n2 = 0; n2 < 4; ++n2)
    w3v[n2] = *(const f32x4*)(w3 + n2 * 16 + g4 * 4);

  const f32x4 zero4 = {0.f, 0.f, 0.f, 0.f};

  // ---- prologue: indices for it=0 ----
  int ib = (l * NB + b0) * NTOK;
  int h0  = Hp[ib + r16] * DIM,   h1  = Hp[ib + 16 + r16] * DIM;
  int rr0 = Rp[ib + r16] * DIM,   rr1 = Rp[ib + 16 + r16] * DIM;
  int t0  = Tp[ib + r16] * DIM,   t1  = Tp[ib + 16 + r16] * DIM;
  int ion = items[b0] * DIM;

#pragma unroll 1
  for (int it = 0; it < BPB; ++it) {
    // ---- raw gathers for this element (B-operand rows; same as R8) ----
    f32x4 axlo[4][2], axhi[4][2];
#pragma unroll
    for (int kk = 0; kk < 4; ++kk)
#pragma unroll
      for (int m2 = 0; m2 < 2; ++m2) {
        const float* src = (kk < 2)
            ? ent + (m2 ? h1 : h0) + kk * 32 + g4 * 8
            : rel + (m2 ? rr1 : rr0) + (kk - 2) * 32 + g4 * 8;
        axlo[kk][m2] = *(const f32x4*)(src);
        axhi[kk][m2] = *(const f32x4*)(src + 4);
      }
    f32x4 iol[2], ioh[2];
    if (w == 0) {
#pragma unroll
      for (int h = 0; h < 2; ++h) {
        iol[h] = *(const f32x4*)(ent + ion + h * 32 + g4 * 8);
        ioh[h] = *(const f32x4*)(ent + ion + h * 32 + g4 * 8 + 4);
      }
    }

    // ---- depth-1 index prefetch ----
    int h0n = h0, h1n = h1, rr0n = rr0, rr1n = rr1, t0n = t0, t1n = t1, ionn = ion;
    if (it + 1 < BPB) {
      const int ibn = ib + NTOK;
      h0n  = Hp[ibn + r16] * DIM;   h1n  = Hp[ibn + 16 + r16] * DIM;
      rr0n = Rp[ibn + r16] * DIM;   rr1n = Rp[ibn + 16 + r16] * DIM;
      t0n  = Tp[ibn + r16] * DIM;   t1n  = Tp[ibn + 16 + r16] * DIM;
      ionn = items[b0 + it + 1] * DIM;
      ib = ibn;
    }

    // ---- wave0: partU = (mean_t u_h0) . io ----
    if (w == 0) {
      float s = 0.f;
#pragma unroll
      for (int j = 0; j < 4; ++j) {
        s += (axlo[0][0][j] + axlo[0][1][j]) * iol[0][j]
           + (axhi[0][0][j] + axhi[0][1][j]) * ioh[0][j]
           + (axlo[1][0][j] + axlo[1][1][j]) * iol[1][j]
           + (axhi[1][0][j] + axhi[1][1][j]) * ioh[1][j];
      }
      s *= (1.f / 32.f);
#pragma unroll
      for (int off = 1; off <= 32; off <<= 1) s += __shfl_xor(s, off);
      if (lane == 0) pu_lds[it] = s;
    }

    // ---- cvt gathers to bf16 B-fragments ----
    bf16x8 bfr[4][2];
#pragma unroll
    for (int kk = 0; kk < 4; ++kk)
#pragma unroll
      for (int m2 = 0; m2 < 2; ++m2) {
        bf16x8 a;
#pragma unroll
        for (int j = 0; j < 4; ++j) {
          a[j]     = (__bf16)axlo[kk][m2][j];
          a[4 + j] = (__bf16)axhi[kk][m2][j];
        }
        bfr[kk][m2] = a;
      }

    // ---- GEMM1' : s1^T[64,32] = W1^T @ x^T (A = weights, B = gathers) ----
    // D layout: lane holds token = 16*m2 + r16, s1col = 16*n + 4*g4 + i.
    f32x4 a1S[2][4], a1G[2][4];
#pragma unroll
    for (int m2 = 0; m2 < 2; ++m2)
#pragma unroll
      for (int n = 0; n < 4; ++n) { a1S[m2][n] = zero4; a1G[m2][n] = zero4; }
#pragma unroll
    for (int kk = 0; kk < 4; ++kk)
#pragma unroll
      for (int n = 0; n < 4; ++n) {
        bf16x8 wS = *(const bf16x8*)(W1t + (n * 16 + r16) * 128 + kk * 32 + g4 * 8);
        bf16x8 wG = *(const bf16x8*)(G1t + (n * 16 + r16) * 128 + kk * 32 + g4 * 8);
#pragma unroll
        for (int m2 = 0; m2 < 2; ++m2) {
          a1S[m2][n] = mfma16(wS, bfr[kk][m2], a1S[m2][n]);
          a1G[m2][n] = mfma16(wG, bfr[kk][m2], a1G[m2][n]);
        }
      }

    // ---- issue t_e loads now (consumed at epilogue): d = 16*n2 + 4*g4 + i ----
    f32x4 te[2][4];
#pragma unroll
    for (int m2 = 0; m2 < 2; ++m2)
#pragma unroll
      for (int n2 = 0; n2 < 4; ++n2)
        te[m2][n2] = *(const f32x4*)(ent + (m2 ? t1 : t0) + n2 * 16 + g4 * 4);

    // ---- S path: pack relu(s1) -> LDS (8 x ds_write_b64) ----
#pragma unroll
    for (int m2 = 0; m2 < 2; ++m2)
#pragma unroll
      for (int n = 0; n < 4; ++n) {
        bf16x4 v;
#pragma unroll
        for (int i = 0; i < 4; ++i) v[i] = (__bf16)fmaxf(a1S[m2][n][i], 0.f);
        *(bf16x4*)&buf[w][m2 * 16 + r16][n * 16 + g4 * 4] = v;
      }

    // GEMM2'-S: s2^T = W2^T @ s1^T  (4 x ds_read_b128)
    f32x4 a2S[2][4];
#pragma unroll
    for (int m2 = 0; m2 < 2; ++m2)
#pragma unroll
      for (int n2 = 0; n2 < 4; ++n2) a2S[m2][n2] = zero4;
#pragma unroll
    for (int kk2 = 0; kk2 < 2; ++kk2) {
      bf16x8 sf[2];
#pragma unroll
      for (int m2 = 0; m2 < 2; ++m2)
        sf[m2] = *(const bf16x8*)&buf[w][m2 * 16 + r16][kk2 * 32 + g4 * 8];
#pragma unroll
      for (int n2 = 0; n2 < 4; ++n2) {
        bf16x8 wS2 = *(const bf16x8*)(W2t + (n2 * 16 + r16) * 64 + kk2 * 32 + g4 * 8);
#pragma unroll
        for (int m2 = 0; m2 < 2; ++m2)
          a2S[m2][n2] = mfma16(wS2, sf[m2], a2S[m2][n2]);
      }
    }

    // ---- softmax: row-dot is in-lane (lane holds 16 s2-cols of its token) ----
    float att2[2];
    {
      float d0[2] = {0.f, 0.f};
#pragma unroll
      for (int m2 = 0; m2 < 2; ++m2)
#pragma unroll
        for (int n2 = 0; n2 < 4; ++n2)
#pragma unroll
          for (int i = 0; i < 4; ++i)
            d0[m2] += fmaxf(a2S[m2][n2][i], 0.f) * w3v[n2][i];
      // reduce over the 4 g4 groups (each holds 16 of the 64 cols)
#pragma unroll
      for (int m2 = 0; m2 < 2; ++m2) {
        d0[m2] += __shfl_xor(d0[m2], 16);
        d0[m2] += __shfl_xor(d0[m2], 32);
        const float sc = 1.f / (1.f + __expf(-d0[m2]));
        att2[m2] = __expf(sc);          // no-max softmax: sc in (0,1)
      }
      float den = att2[0] + att2[1];
#pragma unroll
      for (int off = 1; off <= 8; off <<= 1) den += __shfl_xor(den, off);
      const float inv = 1.f / den;
      att2[0] *= inv; att2[1] *= inv;
    }

    // ---- G path: pack relu(g1) -> LDS (reuse buf) -> GEMM2'-G ----
#pragma unroll
    for (int m2 = 0; m2 < 2; ++m2)
#pragma unroll
      for (int n = 0; n < 4; ++n) {
        bf16x4 v;
#pragma unroll
        for (int i = 0; i < 4; ++i) v[i] = (__bf16)fmaxf(a1G[m2][n][i], 0.f);
        *(bf16x4*)&buf[w][m2 * 16 + r16][n * 16 + g4 * 4] = v;
      }
    f32x4 a2G[2][4];
#pragma unroll
    for (int m2 = 0; m2 < 2; ++m2)
#pragma unroll
      for (int n2 = 0; n2 < 4; ++n2) a2G[m2][n2] = zero4;
#pragma unroll
    for (int kk2 = 0; kk2 < 2; ++kk2) {
      bf16x8 gf[2];
#pragma unroll
      for (int m2 = 0; m2 < 2; ++m2)
        gf[m2] = *(const bf16x8*)&buf[w][m2 * 16 + r16][kk2 * 32 + g4 * 8];
#pragma unroll
      for (int n2 = 0; n2 < 4; ++n2) {
        bf16x8 wG2 = *(const bf16x8*)(G2t + (n2 * 16 + r16) * 64 + kk2 * 32 + g4 * 8);
#pragma unroll
        for (int m2 = 0; m2 < 2; ++m2)
          a2G[m2][n2] = mfma16(wG2, gf[m2], a2G[m2][n2]);
      }
    }

    // ---- epilogue fully in registers: dsum[d] = sum_t att*2sig(g2)*t_e ----
    float dsum[4][4];
#pragma unroll
    for (int n2 = 0; n2 < 4; ++n2)
#pragma unroll
      for (int i = 0; i < 4; ++i) dsum[n2][i] = 0.f;
#pragma unroll
    for (int m2 = 0; m2 < 2; ++m2)
#pragma unroll
      for (int n2 = 0; n2 < 4; ++n2)
#pragma unroll
        for (int i = 0; i < 4; ++i) {
          const float g2v = 2.f / (1.f + __expf(-a2G[m2][n2][i]));
          dsum[n2][i] += att2[m2] * g2v * te[m2][n2][i];
        }
    // reduce over the 16 r16 lanes (tokens)
#pragma unroll
    for (int off = 1; off <= 8; off <<= 1)
#pragma unroll
      for (int n2 = 0; n2 < 4; ++n2)
#pragma unroll
        for (int i = 0; i < 4; ++i)
          dsum[n2][i] += __shfl_xor(dsum[n2][i], off);
    if (r16 == 0) {
#pragma unroll
      for (int n2 = 0; n2 < 4; ++n2)
#pragma unroll
        for (int i = 0; i < 4; ++i)
          outbuf[it][w][n2 * 16 + g4 * 4 + i] = dsum[n2][i];
    }

    // rotate prefetched indices
    h0 = h0n; h1 = h1n; rr0 = rr0n; rr1 = rr1n; t0 = t0n; t1 = t1n; ion = ionn;
  }

  __syncthreads();

  // ---- final combine: wave0 scores all BPB elements ----
  if (w == 0) {
#pragma unroll 1
    for (int bb = 0; bb < BPB; ++bb) {
      float part = outbuf[bb][0][lane] * outbuf[bb][1][lane]
                 + outbuf[bb][2][lane] * outbuf[bb][3][lane];
#pragma unroll
      for (int off = 32; off >= 1; off >>= 1) part += __shfl_xor(part, off);
      if (lane == 0) out[b0 + bb] = 1.f / (1.f + __expf(-(part + pu_lds[bb])));
    }
  }
}

extern "C" void kernel_launch(void* const* d_in, const int* in_sizes, int n_in,
                              void* d_out, int out_size, void* d_ws, size_t ws_size,
                              hipStream_t stream) {
  const int*   items  = (const int*)d_in[1];
  const int*   user_h = (const int*)d_in[2];
  const int*   user_r = (const int*)d_in[3];
  const int*   user_t = (const int*)d_in[4];
  const int*   item_h = (const int*)d_in[5];
  const int*   item_r = (const int*)d_in[6];
  const int*   item_t = (const int*)d_in[7];
  const float* ent    = (const float*)d_in[8];
  const float* rel    = (const float*)d_in[9];
  const float* W1     = (const float*)d_in[10];
  const float* W2     = (const float*)d_in[11];
  const float* w3     = (const float*)d_in[12];
  const float* G1     = (const float*)d_in[13];
  const float* G2     = (const float*)d_in[14];
  __bf16* wsb = (__bf16*)d_ws;   // 48 KB used
  float* out = (float*)d_out;

  prep_w<<<dim3(48), dim3(256), 0, stream>>>(W1, G1, W2, G2, wsb);
  ckan_fast<<<dim3(NB / BPB), dim3(256), 0, stream>>>(
      items, user_h, user_r, user_t, item_h, item_r, item_t,
      ent, rel, wsb, w3, out);
}